// Round 8
// baseline (9225.735 us; speedup 1.0000x reference)
//
#include <hip/hip_runtime.h>
#include <hip/hip_bf16.h>

// StackedMatchLSTM on MI355X — multi-CU scan, LDS-resident weights,
// conflict-free layouts, 6 barriers/step, wave-specialized phases.
// B=32, TP=512, TQ=64, DP=DQ=H=AH=256, NL=2.
// 256 WGs (8 slices x 32 batches) x 512 threads. Slice j owns 32 att cols +
// 128 gate cols (weights in LDS as bf16 uint4, padded rows). Per step:
//   poll h -> load h,x -> [att GEMV (wave0) || gate GEMV (waves1-4)] ->
//   scores (all waves, self-reduced) -> wave0: publish/poll/gather/softmax
//   (waves1-4 idle after banking hwg) -> pre -> gates -> publish h.
// Sync: relaxed agent payload stores + per-slice RMW tag (release-add /
// relaxed add-0 spin) — the r5-r7-proven stable primitive.

#define NB 32
#define TPL 512
#define TQL 64
#define DD 256      // DP = DQ = H = AH
#define H4 1024     // 4*H
#define NC 1280     // AH + 4H
#define NS 8        // slices per batch
#define SC 160      // xpl cols per slice = 32 att + 128 gate
#define GC 128      // gate cols per slice
#define TAGSTR 16   // ints between tags (64 B)

__device__ __forceinline__ float fast_tanh(float x) {
  float xc = fminf(fmaxf(x, -9.f), 9.f);
  float e = __expf(2.f * xc);
  return (e - 1.f) * __builtin_amdgcn_rcpf(e + 1.f);
}
__device__ __forceinline__ float fast_sigmoid(float x) {
  return __builtin_amdgcn_rcpf(1.f + __expf(-x));
}
__device__ __forceinline__ float bflo(unsigned int w) { return __uint_as_float(w << 16); }
__device__ __forceinline__ float bfhi(unsigned int w) { return __uint_as_float(w & 0xffff0000u); }
__device__ __forceinline__ unsigned int packbf(float a, float b) {
  unsigned int lo = __hip_bfloat16_raw(__float2bfloat16(a)).x;
  unsigned int hi = __hip_bfloat16_raw(__float2bfloat16(b)).x;
  return lo | (hi << 16);
}

// ---- agent-scope sync: RMW-only (executes at LLC, stale-proof) --------------
__device__ __forceinline__ float aloadf(const float* p) {
  return __hip_atomic_load(p, __ATOMIC_RELAXED, __HIP_MEMORY_SCOPE_AGENT);
}
__device__ __forceinline__ void astoref(float* p, float v) {
  __hip_atomic_store(p, v, __ATOMIC_RELAXED, __HIP_MEMORY_SCOPE_AGENT);
}
__device__ __forceinline__ void radd(int* p) {
  __hip_atomic_fetch_add(p, 1, __ATOMIC_RELEASE, __HIP_MEMORY_SCOPE_AGENT);
}
__device__ __forceinline__ void spin_ge(int* p, int tgt) {
  int guard = 0;
  while (__hip_atomic_fetch_add(p, 0, __ATOMIC_RELAXED, __HIP_MEMORY_SCOPE_AGENT) < tgt) {
    __builtin_amdgcn_s_sleep(1);
    if (++guard > (1 << 26)) break;   // bail instead of hanging the harness
  }
}

// permuted xpl cols: slice-major blocks of 160: 32 att | f|i|o|g x32
__device__ __forceinline__ int perm_col(int c) {
  if (c < DD) return (c >> 5) * SC + (c & 31);
  int cc = c - DD;
  int g = cc >> 8;          // 0..3 = f,i,o,g
  int m = cc & 255;         // h-elem
  return (m >> 5) * SC + 32 + (g << 5) + (m & 31);
}

// ---- weight prep ------------------------------------------------------------
__global__ __launch_bounds__(256) void pack_weights(
    const float* __restrict__ Wp, const float* __restrict__ Wq,
    const float* __restrict__ Wl,
    float* __restrict__ wx, float* __restrict__ wqv)
{
  int d = blockIdx.y;
  int idx = blockIdx.x * 256 + threadIdx.x;
  if (idx >= DD * NC) return;
  int k = idx / NC, j = idx % NC;
  int o = d * DD * NC + idx;
  const float* Wld = Wl + (size_t)d * 768 * H4;
  if (j < DD) {
    int s = d * DD * DD + k * DD + j;
    wx[o] = Wp[s]; wqv[o] = Wq[s];
  } else {
    int c = j - DD;
    wx[o]  = Wld[(size_t)k * H4 + c];
    wqv[o] = Wld[(size_t)(DD + k) * H4 + c];
  }
}

// attl[((d*8+j)*32 + kq4)*32 + col]: uint4 = 8 consecutive k of W_att_r
__global__ __launch_bounds__(256) void pack_attl(
    const float* __restrict__ Wr, uint4* __restrict__ attl)
{
  int idx = blockIdx.x * 256 + threadIdx.x;       // 2*8*32*32 = 16384
  if (idx >= 2 * NS * 32 * 32) return;
  int col = idx & 31; int r = idx >> 5;
  int kq4 = r & 31; r >>= 5;
  int j = r & 7; int d = r >> 3;
  float v[8];
  #pragma unroll
  for (int kr = 0; kr < 8; ++kr)
    v[kr] = Wr[((size_t)d * DD + kq4 * 8 + kr) * DD + (j << 5) + col];
  attl[idx] = make_uint4(packbf(v[0], v[1]), packbf(v[2], v[3]),
                         packbf(v[4], v[5]), packbf(v[6], v[7]));
}

// gatel[((d*8+j)*32 + kq4)*128 + col]: uint4 = 8 k of Wl h-part col (g,j,pos)
__global__ __launch_bounds__(256) void pack_gatel(
    const float* __restrict__ Wl, uint4* __restrict__ gatel)
{
  int idx = blockIdx.x * 256 + threadIdx.x;       // 2*8*32*128 = 65536
  if (idx >= 2 * NS * 32 * GC) return;
  int col = idx & 127; int r = idx >> 7;
  int kq4 = r & 31; r >>= 5;
  int j = r & 7; int d = r >> 3;
  int g = col >> 5, pos = col & 31;
  float v[8];
  #pragma unroll
  for (int kr = 0; kr < 8; ++kr) {
    int k = kq4 * 8 + kr;
    v[kr] = Wl[((size_t)d * 768 + 512 + k) * H4 + (g << 8) + (j << 5) + pos];
  }
  gatel[idx] = make_uint4(packbf(v[0], v[1]), packbf(v[2], v[3]),
                          packbf(v[4], v[5]), packbf(v[6], v[7]));
}

// ---- C[M][1280] = A[M][256] @ B[256][1280], fp32 ----------------------------
template <bool PERM>
__global__ __launch_bounds__(256) void sgemm(
    const float* __restrict__ A, const float* __restrict__ Bm,
    float* __restrict__ C)
{
  __shared__ float As[16][65];
  __shared__ float Bs[16][64];
  int tid = threadIdx.x;
  int tx = tid & 15, ty = tid >> 4;
  int col0 = blockIdx.x * 64, row0 = blockIdx.y * 64;
  float acc[4][4] = {};
  for (int kt = 0; kt < DD; kt += 16) {
    #pragma unroll
    for (int i = 0; i < 4; ++i) {
      int e = tid + i * 256;
      As[e & 15][e >> 4] = A[(size_t)(row0 + (e >> 4)) * DD + kt + (e & 15)];
      Bs[e >> 6][e & 63] = Bm[(size_t)(kt + (e >> 6)) * NC + col0 + (e & 63)];
    }
    __syncthreads();
    #pragma unroll
    for (int kk = 0; kk < 16; ++kk) {
      float a[4], bv[4];
      #pragma unroll
      for (int i = 0; i < 4; ++i) a[i] = As[kk][ty * 4 + i];
      #pragma unroll
      for (int jj = 0; jj < 4; ++jj) bv[jj] = Bs[kk][tx * 4 + jj];
      #pragma unroll
      for (int i = 0; i < 4; ++i)
        #pragma unroll
        for (int jj = 0; jj < 4; ++jj)
          acc[i][jj] = fmaf(a[i], bv[jj], acc[i][jj]);
    }
    __syncthreads();
  }
  #pragma unroll
  for (int i = 0; i < 4; ++i)
    #pragma unroll
    for (int jj = 0; jj < 4; ++jj) {
      int c = col0 + tx * 4 + jj;
      int cc = PERM ? perm_col(c) : c;
      C[(size_t)(row0 + ty * 4 + i) * NC + cc] = acc[i][jj];
    }
}

// ---- scan: 256 WGs x 512 threads --------------------------------------------
__global__ __launch_bounds__(512, 1) void scan(
    const float* __restrict__ xpl,    // [NB*TP][NC] permuted cols
    const float* __restrict__ qv,     // [NB*TQ][NC] plain (this layer)
    const uint4* __restrict__ attl,   // this layer's [8][32][32]
    const uint4* __restrict__ gatel,  // this layer's [8][32][128]
    const float* __restrict__ wa,     // [256]
    const float* __restrict__ bias_f,
    const float* __restrict__ bias_iog,
    const float* __restrict__ mask_p,
    const float* __restrict__ mask_q,
    float* __restrict__ xch_s,        // [NB][NS][64]
    float* __restrict__ xch_h,        // [NB][256]
    int* __restrict__ tag_s,          // [NB][NS] stride TAGSTR
    int* __restrict__ tag_h,          // [NB][NS] stride TAGSTR
    float* __restrict__ out,          // [NB*TP][256]
    int lbase)                        // layer*TPL
{
  const int bid = blockIdx.x;
  const int j = bid & 7, b = bid >> 3;
  const int tid = threadIdx.x;
  const int lane = tid & 63;

  // padded, conflict-free layouts (odd quad counts per row)
  __shared__ uint4 wg4[32][129];        // 66.0 KB gate weights
  __shared__ uint4 wat4[32][33];        // 16.9 KB att weights
  __shared__ unsigned int vl_l[GC][33]; // 16.9 KB Vl bf16 pairs [col][tq/2]
  __shared__ float qT[32][65];          //  8.3 KB qWq^T (own att cols)
  __shared__ __align__(16) float h_lds[DD];
  __shared__ float xsl[SC];
  __shared__ float hw_att[32], waa[32];
  __shared__ float sc_s[TQL], al_s[TQL];
  __shared__ float pre_s[GC], bias_s[GC], c_sh[32];

  const float* qv_b = qv + (size_t)b * TQL * NC;
  float* xch_s_b = xch_s + b * (NS * TQL);
  float* xch_h_b = xch_h + b * DD;
  int* tags_s = tag_s + b * NS * TAGSTR;
  int* tags_h = tag_h + b * NS * TAGSTR;

  // ---- one-time preload
  {
    const uint4* gp = gatel + (size_t)j * 32 * GC;
    for (int i = tid; i < 32 * GC; i += 512) wg4[i >> 7][i & 127] = gp[i];
    const uint4* ap = attl + (size_t)j * 32 * 32;
    for (int i = tid; i < 32 * 32; i += 512) wat4[i >> 5][i & 31] = ap[i];
    for (int i = tid; i < TQL * 32; i += 512) {
      int tq = i >> 5, a = i & 31;
      qT[a][tq] = qv_b[(size_t)tq * NC + (j << 5) + a];
    }
    for (int i = tid; i < GC * 32; i += 512) {
      int col = i >> 5, tw = i & 31;
      int g = col >> 5, m = (j << 5) + (col & 31);
      float v0 = qv_b[(size_t)(2 * tw) * NC + DD + (g << 8) + m];
      float v1 = qv_b[(size_t)(2 * tw + 1) * NC + DD + (g << 8) + m];
      vl_l[col][tw] = packbf(v0, v1);
    }
    if (tid < 32) { waa[tid] = wa[(j << 5) + tid]; c_sh[tid] = 0.f; }
    if (tid < GC) {
      int g = tid >> 5, m = (j << 5) + (tid & 31);
      bias_s[tid] = (g == 0) ? bias_f[m] : bias_iog[((g - 1) << 8) + m];
    }
  }
  float mq = mask_q[b * TQL + lane];    // wave 0 (lane==tid) uses in softmax
  __syncthreads();

  for (int t = 0; t < TPL; ++t) {
    const float* xrow = xpl + ((size_t)b * TPL + t) * NC + j * SC;
    float xv = (tid >= 320 && tid < 480) ? xrow[tid - 320] : 0.f;  // prefetch
    float mtv = mask_p[b * TPL + t];

    // ---- wait for h[t] (wave-0 lanes 0..7 poll), then load h,x to LDS
    if (t > 0 && tid < NS) spin_ge(&tags_h[tid * TAGSTR], lbase + t);
    __syncthreads();                   // B0: tags ok; prev-step LDS uses done
    if (tid < DD) h_lds[tid] = (t > 0) ? aloadf(xch_h_b + tid) : 0.f;
    if (tid >= 320 && tid < 480) xsl[tid - 320] = xv;
    __syncthreads();                   // B1: h_lds, xsl ready

    // ---- concurrent GEMVs: wave 0 att (2 thr/col), waves 1-4 gate (2 thr/col)
    float hwg = 0.f;
    if (tid < 64) {
      int col = tid >> 1, half = tid & 1;
      float a0 = 0.f, a1 = 0.f;
      #pragma unroll
      for (int i = 0; i < 16; ++i) {
        int kq4 = i * 2 + half;                  // interleaved k-split
        uint4 w = wat4[kq4][col];
        float4 h0 = *(const float4*)&h_lds[kq4 * 8];
        float4 h1 = *(const float4*)&h_lds[kq4 * 8 + 4];
        a0 = fmaf(h0.x, bflo(w.x), a0); a1 = fmaf(h0.y, bfhi(w.x), a1);
        a0 = fmaf(h0.z, bflo(w.y), a0); a1 = fmaf(h0.w, bfhi(w.y), a1);
        a0 = fmaf(h1.x, bflo(w.z), a0); a1 = fmaf(h1.y, bfhi(w.z), a1);
        a0 = fmaf(h1.z, bflo(w.w), a0); a1 = fmaf(h1.w, bfhi(w.w), a1);
      }
      float aw = a0 + a1;
      aw += __shfl_xor(aw, 1);
      if (half == 0) hw_att[col] = aw;
    } else if (tid < 320) {
      int t4 = tid - 64, gcol = t4 >> 1, gh = t4 & 1;
      float g0 = 0.f, g1 = 0.f;
      #pragma unroll
      for (int i = 0; i < 16; ++i) {
        int kq4 = i * 2 + gh;                    // interleaved k-split
        uint4 w = wg4[kq4][gcol];
        float4 h0 = *(const float4*)&h_lds[kq4 * 8];
        float4 h1 = *(const float4*)&h_lds[kq4 * 8 + 4];
        g0 = fmaf(h0.x, bflo(w.x), g0); g1 = fmaf(h0.y, bfhi(w.x), g1);
        g0 = fmaf(h0.z, bflo(w.y), g0); g1 = fmaf(h0.w, bfhi(w.y), g1);
        g0 = fmaf(h1.x, bflo(w.z), g0); g1 = fmaf(h1.y, bfhi(w.z), g1);
        g0 = fmaf(h1.z, bflo(w.w), g0); g1 = fmaf(h1.w, bfhi(w.w), g1);
      }
      hwg = g0 + g1;
      hwg += __shfl_xor(hwg, 1);       // both partners hold full hw_gate[gcol]
    }
    __syncthreads();                   // B2: hw_att ready

    // ---- scores: each wave computes its 8 tq fully (8 col-chunks x 4 cols)
    {
      int wv = tid >> 6, tql = lane & 7, asub = lane >> 3;
      int tq = wv * 8 + tql;
      float p = 0.f;
      #pragma unroll
      for (int i = 0; i < 4; ++i) {
        int a = asub * 4 + i;
        p = fmaf(fast_tanh(qT[a][tq] + xsl[a] + hw_att[a]), waa[a], p);
      }
      p += __shfl_xor(p, 8);
      p += __shfl_xor(p, 16);
      p += __shfl_xor(p, 32);
      if (asub == 0) sc_s[tq] = p;
    }
    __syncthreads();                   // B3: sc_s ready

    // ---- wave 0: publish -> poll -> gather -> softmax (others done w/ hwg)
    if (tid < 64) {
      astoref(xch_s_b + (j << 6) + tid, sc_s[tid]);
      if (tid == 0) radd(&tags_s[j * TAGSTR]);     // release: drains stores
      if (tid < NS) spin_ge(&tags_s[tid * TAGSTR], lbase + t + 1);
      float v = 0.f;
      #pragma unroll
      for (int q = 0; q < NS; ++q) v += aloadf(xch_s_b + (q << 6) + tid);
      v = (mq > 0.f) ? v : -1e9f;
      float m = v;
      #pragma unroll
      for (int off = 32; off > 0; off >>= 1) m = fmaxf(m, __shfl_xor(m, off));
      float p = __expf(v - m);
      float su = p;
      #pragma unroll
      for (int off = 32; off > 0; off >>= 1) su += __shfl_xor(su, off);
      al_s[tid] = p * __builtin_amdgcn_rcpf(su);
    }
    __syncthreads();                   // B4: al_s ready

    // ---- pre: waves 1-4 (hold hwg): alpha@Vl 2-way tq split
    if (tid >= 64 && tid < 320) {
      int t4 = tid - 64, gcol = t4 >> 1, gh = t4 & 1;
      float d0 = 0.f, d1 = 0.f;
      #pragma unroll
      for (int i = 0; i < 16; ++i) {
        int tw = gh * 16 + i;
        unsigned int v = vl_l[gcol][tw];
        d0 = fmaf(al_s[2 * tw], bflo(v), d0);
        d1 = fmaf(al_s[2 * tw + 1], bfhi(v), d1);
      }
      float dd = d0 + d1;
      dd += __shfl_xor(dd, 1);
      if (gh == 0)
        pre_s[gcol] = hwg + dd + xsl[32 + gcol] + bias_s[gcol];
    }
    __syncthreads();                   // B5: pre ready

    // ---- gates + state (wave 0, lanes 0..31); publish h slice + tag
    if (tid < 32) {
      float f  = pre_s[tid];
      float ii = pre_s[32 + tid];
      float oo = pre_s[64 + tid];
      float g  = pre_s[96 + tid];
      int m = (j << 5) + tid;
      float c0 = c_sh[tid], h0 = h_lds[m];
      float c1 = fast_sigmoid(f) * c0 + fast_sigmoid(ii) * fast_tanh(g);
      c1 = c1 * mtv + c0 * (1.f - mtv);
      float h1 = fast_sigmoid(oo) * fast_tanh(c1);
      h1 = h1 * mtv + h0 * (1.f - mtv);
      c_sh[tid] = c1;
      astoref(xch_h_b + m, h1);        // payload straight to LLC
      if (tid == 0) radd(&tags_h[j * TAGSTR]);   // release drains wave stores
      out[((size_t)b * TPL + t) * DD + m] = h1;
    }
    // no trailing barrier: next iteration's B0 orders h_lds reuse
  }
}

// -----------------------------------------------------------------------------
extern "C" void kernel_launch(void* const* d_in, const int* in_sizes, int n_in,
                              void* d_out, int out_size, void* d_ws, size_t ws_size,
                              hipStream_t stream) {
  const float* input_p  = (const float*)d_in[0];
  const float* mask_p   = (const float*)d_in[1];
  const float* input_q  = (const float*)d_in[2];
  const float* mask_q   = (const float*)d_in[3];
  const float* W_att_p  = (const float*)d_in[4];
  const float* W_att_q  = (const float*)d_in[5];
  const float* W_att_r  = (const float*)d_in[6];
  const float* w_att    = (const float*)d_in[7];
  const float* W_lstm   = (const float*)d_in[8];
  const float* bias_f   = (const float*)d_in[9];
  const float* bias_iog = (const float*)d_in[10];
  float* out = (float*)d_out;
  float* ws  = (float*)d_ws;
  (void)ws_size; (void)in_sizes; (void)n_in; (void)out_size;

  const size_t SZ_XPL  = (size_t)NB * TPL * NC;
  const size_t SZ_QV   = (size_t)NB * TQL * NC;
  const size_t SZ_W    = (size_t)DD * NC;
  const size_t SZ_ATTL = (size_t)NS * 32 * 32;    // uint4 per layer
  const size_t SZ_GATL = (size_t)NS * 32 * GC;    // uint4 per layer

  float* ws_xpl = ws;
  float* ws_qv  = ws_xpl + SZ_XPL;
  float* ws_wx  = ws_qv  + 2 * SZ_QV;
  float* ws_wqv = ws_wx  + 2 * SZ_W;
  float* ws_o0  = ws_wqv + 2 * SZ_W;
  uint4* ws_attl = (uint4*)(ws_o0 + (size_t)NB * TPL * DD);
  uint4* ws_gatl = ws_attl + 2 * SZ_ATTL;
  float* ws_xs   = (float*)(ws_gatl + 2 * SZ_GATL);  // xch_s [NB][8][64]
  float* ws_xh   = ws_xs + NB * NS * TQL;            // xch_h [NB][256]
  int*   ws_tag  = (int*)(ws_xh + NB * DD);
  int*   tag_s   = ws_tag;                           // [NB][NS] x TAGSTR
  int*   tag_h   = ws_tag + NB * NS * TAGSTR;

  dim3 gpack((DD * NC + 255) / 256, 2);
  pack_weights<<<gpack, 256, 0, stream>>>(W_att_p, W_att_q, W_lstm, ws_wx, ws_wqv);
  pack_attl<<<(2 * NS * 32 * 32 + 255) / 256, 256, 0, stream>>>(W_att_r, ws_attl);
  pack_gatel<<<(2 * NS * 32 * GC + 255) / 256, 256, 0, stream>>>(W_lstm, ws_gatl);
  hipMemsetAsync(ws_tag, 0, 2 * NB * NS * TAGSTR * sizeof(int), stream);

  for (int d = 0; d < 2; ++d) {
    dim3 g(NC / 64, (NB * TQL) / 64);
    sgemm<false><<<g, 256, 0, stream>>>(input_q, ws_wqv + d * SZ_W, ws_qv + d * SZ_QV);
  }

  // layer 0
  {
    dim3 g(NC / 64, (NB * TPL) / 64);
    sgemm<true><<<g, 256, 0, stream>>>(input_p, ws_wx, ws_xpl);
    scan<<<NB * NS, 512, 0, stream>>>(ws_xpl, ws_qv, ws_attl, ws_gatl,
                                      w_att, bias_f, bias_iog, mask_p, mask_q,
                                      ws_xs, ws_xh, tag_s, tag_h, ws_o0, 0);
  }
  // layer 1
  {
    dim3 g(NC / 64, (NB * TPL) / 64);
    sgemm<true><<<g, 256, 0, stream>>>(ws_o0, ws_wx + SZ_W, ws_xpl);
    scan<<<NB * NS, 512, 0, stream>>>(ws_xpl, ws_qv + SZ_QV, ws_attl + SZ_ATTL,
                                      ws_gatl + SZ_GATL, w_att + DD, bias_f + DD,
                                      bias_iog + 3 * DD, mask_p, mask_q,
                                      ws_xs, ws_xh, tag_s, tag_h, out, TPL);
  }
}